// Round 3
// baseline (577.907 us; speedup 1.0000x reference)
//
#include <hip/hip_runtime.h>
#include <hip/hip_bf16.h>

// Problem constants: N=16, M=65536, FIN=32, FOUT=32, K=7
#define N_    16
#define M_    65536
#define FIN_  32
#define FOUT_ 32
#define K_    7

#define BLOCKS_   2048
#define THREADS_  256
#define CHUNK_M_  256                 // m per ticket
#define CHUNKS_   (M_ / CHUNK_M_)     // 256 tickets per n-slice
#define ITERS_C_  4                   // 64 m per wave per chunk / 16

typedef __bf16 bf16x8 __attribute__((ext_vector_type(8)));
typedef float  f32x4  __attribute__((ext_vector_type(4)));

// Per-(launch, slice) ticket queues. [0..7] = launch 0, [8..15] = launch 1.
// Zeroed by the convert kernel every graph replay (runs before both gfc
// launches on the same stream).
__device__ int g_tickets[16];

// ---------------------------------------------------------------------------
// Pass 1: streaming fp32 -> bf16 convert, same (N,M,FIN) layout.
// Each n-slice xb[n] = 4 MB = exactly one XCD L2.
// x loads nontemporal (dead after this); xb stores REGULAR (LLC-resident —
// round-1 lesson). Block 0 also re-zeroes the ticket queues.
// ---------------------------------------------------------------------------
__global__ __launch_bounds__(256)
void convert_kernel(const float* __restrict__ x, __bf16* __restrict__ xb)
{
    if (blockIdx.x == 0 && threadIdx.x < 16) g_tickets[threadIdx.x] = 0;

    const size_t tid = (size_t)blockIdx.x * blockDim.x + threadIdx.x;
    const f32x4* src = (const f32x4*)x + tid * 2;
    const f32x4 v0 = __builtin_nontemporal_load(src);
    const f32x4 v1 = __builtin_nontemporal_load(src + 1);
    bf16x8 b;
    #pragma unroll
    for (int j = 0; j < 4; ++j) b[j] = (__bf16)v0[j];
    #pragma unroll
    for (int j = 0; j < 4; ++j) b[4 + j] = (__bf16)v1[j];
    *(bf16x8*)(xb + tid * 8) = b;
}

// ---------------------------------------------------------------------------
// Pass 2 (x2 launches): XCD-exact L2-resident gathers.
//   - Each block reads its REAL XCD id (HW_REG_XCC_ID) and drains that XCD's
//     ticket queue: tickets cover the m-sweep of slice n = launch*8 + xcd.
//     Working set per XCD = 4 MB = its private L2; 14x reuse per line.
//   - Work-stealing over the other queues guarantees completion regardless
//     of block->XCD balance or a misread XCC id (perf degrades, not wrong).
//   - Kernel boundary between launches = hard phase separation (no drift).
//   - Gathers are regular loads (want L2 allocation); out stores nontemporal.
// ---------------------------------------------------------------------------
__global__ __launch_bounds__(256, 4)
void gfc_loc_kernel(const __bf16* __restrict__ xb,
                    const float* __restrict__ w,
                    const float* __restrict__ bias,
                    const int*   __restrict__ il,
                    const float* __restrict__ iv,
                    float* __restrict__ out,
                    const int launch)
{
    __shared__ __bf16 wlds[K_ * 2 * 64 * 8];   // [k][h][lane][8] = 14 KB
    __shared__ int t_sh;

    const int lane = threadIdx.x & 63;
    const int col  = lane & 15;   // A-row (m offset in group) / C-col (o)
    const int kgrp = lane >> 4;   // 8-wide f-chunk
    const int wv   = threadIdx.x >> 6;

    // Stage B fragments once per block: frag[k][h][lane][j] = w[k][kg*8+j][h*16+c]
    for (int t = threadIdx.x; t < K_ * 2 * 64; t += THREADS_) {
        const int l  = t & 63;
        const int h  = (t >> 6) & 1;
        const int k  = t >> 7;
        const int c  = l & 15;
        const int kg = l >> 4;
        const float* wp = w + (size_t)k * (FIN_ * FOUT_)
                            + (size_t)(kg * 8) * FOUT_ + h * 16 + c;
        bf16x8 b;
        #pragma unroll
        for (int j = 0; j < 8; ++j) b[j] = (__bf16)wp[j * FOUT_];
        *(bf16x8*)(wlds + (size_t)t * 8) = b;
    }
    __syncthreads();

    const float b_lo = bias[col];
    const float b_hi = bias[16 + col];

    unsigned xcc_raw;
    asm volatile("s_getreg_b32 %0, hwreg(HW_REG_XCC_ID, 0, 32)" : "=s"(xcc_raw));
    const int xcc = (int)(xcc_raw & 7u);

    for (int s = 0; s < 8; ++s) {
        const int q = (xcc + s) & 7;          // own slice first, then steal
        const int n = launch * 8 + q;
        const __bf16* xn = xb + ((size_t)n << 21);   // n * M_ * FIN_ elements
        int* tq = &g_tickets[launch * 8 + q];

        for (;;) {
            __syncthreads();                  // protect t_sh reuse
            if (threadIdx.x == 0) t_sh = atomicAdd(tq, 1);
            __syncthreads();
            const int t = t_sh;
            if (t >= CHUNKS_) break;

            const int m_base = t * CHUNK_M_ + wv * 64;   // wave's 64 m

            // ---- pipelined 4 iterations of 16 m ----
            float ivs[K_];
            bf16x8 raw[K_];
            {
                const int m0 = m_base + col;
                int idx0[K_];
                #pragma unroll
                for (int k = 0; k < K_; ++k) {
                    idx0[k] = il[m0 * K_ + k];
                    ivs[k]  = iv[m0 * K_ + k];
                }
                #pragma unroll
                for (int k = 0; k < K_; ++k)
                    raw[k] = *(const bf16x8*)(xn + (size_t)idx0[k] * FIN_ + kgrp * 8);
            }

            #pragma unroll
            for (int it = 0; it < ITERS_C_; ++it) {
                const bool hn = (it + 1) < ITERS_C_;

                // 1) next iteration's idx/iv
                int   idxn[K_];
                float ivn[K_];
                if (hn) {
                    const int mn = m_base + (it + 1) * 16 + col;
                    #pragma unroll
                    for (int k = 0; k < K_; ++k) {
                        idxn[k] = il[mn * K_ + k];
                        ivn[k]  = iv[mn * K_ + k];
                    }
                }

                // 2) compute with gathers issued one iteration ago
                f32x4 acc0 = {0.f, 0.f, 0.f, 0.f};
                f32x4 acc1 = {0.f, 0.f, 0.f, 0.f};
                #pragma unroll
                for (int k = 0; k < K_; ++k) {
                    const float ivk = ivs[k];
                    bf16x8 a;
                    #pragma unroll
                    for (int j = 0; j < 8; ++j)
                        a[j] = (__bf16)((float)raw[k][j] * ivk);
                    const bf16x8 bf0 = *(const bf16x8*)(wlds + ((k * 2 + 0) * 64 + lane) * 8);
                    const bf16x8 bf1 = *(const bf16x8*)(wlds + ((k * 2 + 1) * 64 + lane) * 8);
                    acc0 = __builtin_amdgcn_mfma_f32_16x16x32_bf16(a, bf0, acc0, 0, 0, 0);
                    acc1 = __builtin_amdgcn_mfma_f32_16x16x32_bf16(a, bf1, acc1, 0, 0, 0);
                }

                // 3) issue next iteration's gathers
                if (hn) {
                    #pragma unroll
                    for (int k = 0; k < K_; ++k)
                        raw[k] = *(const bf16x8*)(xn + (size_t)idxn[k] * FIN_ + kgrp * 8);
                    #pragma unroll
                    for (int k = 0; k < K_; ++k) ivs[k] = ivn[k];
                }

                // 4) epilogue: D row = m offset (kgrp*4+r), D col = o.
                //    2 KB contiguous per iteration; nontemporal (write-once).
                const int mb = m_base + it * 16;
                #pragma unroll
                for (int r = 0; r < 4; ++r) {
                    float* op = out + ((size_t)n * M_ + (size_t)(mb + kgrp * 4 + r)) * FOUT_;
                    __builtin_nontemporal_store(acc0[r] + b_lo, op + col);
                    __builtin_nontemporal_store(acc1[r] + b_hi, op + 16 + col);
                }
            }
        }
    }
}

// ---------------------------------------------------------------------------
// Fallback (round-1 kernel) if ws_size is too small for the bf16 staging.
// ---------------------------------------------------------------------------
__global__ __launch_bounds__(256, 4)
void gfc_fallback_kernel(const float* __restrict__ x,
                         const float* __restrict__ w,
                         const float* __restrict__ bias,
                         const int*   __restrict__ index_list,
                         const float* __restrict__ index_value,
                         float* __restrict__ out)
{
    const int lane  = threadIdx.x & 63;
    const int col   = lane & 15;
    const int kgrp  = lane >> 4;

    const int waves_per_block = blockDim.x >> 6;
    const int wave_id     = blockIdx.x * waves_per_block + (threadIdx.x >> 6);
    const int total_waves = gridDim.x * waves_per_block;

    bf16x8 bfrag[K_][2];
    #pragma unroll
    for (int k = 0; k < K_; ++k) {
        #pragma unroll
        for (int h = 0; h < 2; ++h) {
            const float* wp = w + (size_t)k * (FIN_ * FOUT_)
                                + (size_t)(kgrp * 8) * FOUT_ + h * 16 + col;
            bf16x8 b;
            #pragma unroll
            for (int j = 0; j < 8; ++j)
                b[j] = (__bf16)wp[j * FOUT_];
            bfrag[k][h] = b;
        }
    }
    const float b_lo = bias[col];
    const float b_hi = bias[16 + col];

    for (int m = wave_id; m < M_; m += total_waves) {
        f32x4 acc0 = {0.f, 0.f, 0.f, 0.f};
        f32x4 acc1 = {0.f, 0.f, 0.f, 0.f};

        #pragma unroll
        for (int k = 0; k < K_; ++k) {
            const int   m2  = index_list[m * K_ + k];
            const float ivk = index_value[m * K_ + k];
            const float* ap = x + ((size_t)col * M_ + (size_t)m2) * FIN_ + kgrp * 8;
            const float4 v0 = *(const float4*)(ap);
            const float4 v1 = *(const float4*)(ap + 4);
            const float av[8] = {v0.x, v0.y, v0.z, v0.w, v1.x, v1.y, v1.z, v1.w};
            bf16x8 a;
            #pragma unroll
            for (int j = 0; j < 8; ++j)
                a[j] = (__bf16)(av[j] * ivk);
            acc0 = __builtin_amdgcn_mfma_f32_16x16x32_bf16(a, bfrag[k][0], acc0, 0, 0, 0);
            acc1 = __builtin_amdgcn_mfma_f32_16x16x32_bf16(a, bfrag[k][1], acc1, 0, 0, 0);
        }

        #pragma unroll
        for (int r = 0; r < 4; ++r) {
            const int n = kgrp * 4 + r;
            const size_t base = ((size_t)n * M_ + (size_t)m) * FOUT_;
            out[base + col]      = acc0[r] + b_lo;
            out[base + 16 + col] = acc1[r] + b_hi;
        }
    }
}

extern "C" void kernel_launch(void* const* d_in, const int* in_sizes, int n_in,
                              void* d_out, int out_size, void* d_ws, size_t ws_size,
                              hipStream_t stream) {
    const float* x    = (const float*)d_in[0];  // (N, M, FIN) fp32
    const float* w    = (const float*)d_in[1];  // (K, FIN, FOUT) fp32
    const float* bias = (const float*)d_in[2];  // (FOUT,) fp32
    const int*   il   = (const int*)  d_in[3];  // (M*K,) int32
    const float* iv   = (const float*)d_in[4];  // (M, K) fp32
    float* out = (float*)d_out;                 // (N, M, FOUT) fp32

    const size_t ws_needed = (size_t)M_ * N_ * FIN_ * sizeof(__bf16);  // 64 MB
    if (ws_size >= ws_needed) {
        __bf16* xb = (__bf16*)d_ws;
        const int t_total = N_ * M_ * FIN_ / 8;   // 4,194,304 threads
        hipLaunchKernelGGL(convert_kernel, dim3(t_total / 256), dim3(256), 0, stream,
                           x, xb);
        hipLaunchKernelGGL(gfc_loc_kernel, dim3(BLOCKS_), dim3(THREADS_), 0, stream,
                           xb, w, bias, il, iv, out, 0);
        hipLaunchKernelGGL(gfc_loc_kernel, dim3(BLOCKS_), dim3(THREADS_), 0, stream,
                           xb, w, bias, il, iv, out, 1);
    } else {
        hipLaunchKernelGGL(gfc_fallback_kernel, dim3(2048), dim3(256), 0, stream,
                           x, w, bias, il, iv, out);
    }
}

// Round 4
// 367.026 us; speedup vs baseline: 1.5746x; 1.5746x over previous
//
#include <hip/hip_runtime.h>
#include <hip/hip_bf16.h>

// Problem constants: N=16, M=65536, FIN=32, FOUT=32, K=7
#define N_    16
#define M_    65536
#define FIN_  32
#define FOUT_ 32
#define K_    7

#define BLOCKS_   2048
#define THREADS_  256
#define ITERS_    8        // 2 n-phases x 4 m-iterations, one flat pipeline

typedef __bf16 bf16x8 __attribute__((ext_vector_type(8)));
typedef float  f32x4  __attribute__((ext_vector_type(4)));

// ---------------------------------------------------------------------------
// Pass 1: streaming fp32 -> bf16 convert, same (N,M,FIN) layout.
// Each n-slice xb[n] = 4 MB = one XCD L2's worth.
// x loads nontemporal (dead after this); xb stores REGULAR (LLC-resident).
// ---------------------------------------------------------------------------
__global__ __launch_bounds__(256)
void convert_kernel(const float* __restrict__ x, __bf16* __restrict__ xb)
{
    const size_t tid = (size_t)blockIdx.x * blockDim.x + threadIdx.x;
    const f32x4* src = (const f32x4*)x + tid * 2;
    const f32x4 v0 = __builtin_nontemporal_load(src);
    const f32x4 v1 = __builtin_nontemporal_load(src + 1);
    bf16x8 b;
    #pragma unroll
    for (int j = 0; j < 4; ++j) b[j] = (__bf16)v0[j];
    #pragma unroll
    for (int j = 0; j < 4; ++j) b[4 + j] = (__bf16)v1[j];
    *(bf16x8*)(xb + tid * 8) = b;
}

// ---------------------------------------------------------------------------
// Pass 2: XCD-local phased gathers, round-0 pipeline structure.
//   - Co-residency group g = blockIdx&7 (round-robin dispatch puts all blocks
//     of a group on one XCD). Group g sweeps ALL m for n=2g (iters 0..3),
//     then n=2g+1 (iters 4..7). Concurrent gather working set per XCD =
//     one 4 MB read-only slice -> cached in that XCD's private L2
//     (round-3 FETCH evidence: 62 MB/launch, near the cold floor).
//   - NO atomics, NO per-iter barriers (round-3 lesson: orchestration
//     latency, not memory, was the 229 us). Phase discipline comes from
//     identical per-wave work. Flat 8-iter software pipeline: idx/iv and
//     gathers for iteration i+1 (including across the phase boundary) are
//     in flight while computing iteration i.
//   - B fragments in LDS (14 KB); out stores nontemporal (write-once).
// ---------------------------------------------------------------------------
__global__ __launch_bounds__(256, 4)
void gfc_phase_kernel(const __bf16* __restrict__ xb,
                      const float* __restrict__ w,
                      const float* __restrict__ bias,
                      const int*   __restrict__ il,
                      const float* __restrict__ iv,
                      float* __restrict__ out)
{
    __shared__ __bf16 wlds[K_ * 2 * 64 * 8];   // [k][h][lane][8] = 14 KB

    const int lane = threadIdx.x & 63;
    const int col  = lane & 15;   // A-row (m offset in group of 16) / C-col (o)
    const int kgrp = lane >> 4;   // 8-wide f-chunk

    // Stage B fragments once per block: frag[k][h][lane][j] = w[k][kg*8+j][h*16+c]
    for (int t = threadIdx.x; t < K_ * 2 * 64; t += THREADS_) {
        const int l  = t & 63;
        const int h  = (t >> 6) & 1;
        const int k  = t >> 7;
        const int c  = l & 15;
        const int kg = l >> 4;
        const float* wp = w + (size_t)k * (FIN_ * FOUT_)
                            + (size_t)(kg * 8) * FOUT_ + h * 16 + c;
        bf16x8 b;
        #pragma unroll
        for (int j = 0; j < 8; ++j) b[j] = (__bf16)wp[j * FOUT_];
        *(bf16x8*)(wlds + (size_t)t * 8) = b;
    }
    __syncthreads();

    const float b_lo = bias[col];
    const float b_hi = bias[16 + col];

    const int grp  = blockIdx.x & 7;                                   // slice group
    const int widx = (blockIdx.x >> 3) * 4 + (threadIdx.x >> 6);       // 0..1023
    const int mb0  = widx * 64;   // wave's 64-m stripe, revisited per phase

    // iteration it: n = grp*2 + (it>>2), m = mb0 + (it&3)*16 + col
    // ---- Pipeline prologue: idx/iv + gathers for it=0 ----
    int   idxs[K_];
    float ivs[K_];
    {
        const int m0 = mb0 + col;
        #pragma unroll
        for (int k = 0; k < K_; ++k) {
            idxs[k] = il[m0 * K_ + k];
            ivs[k]  = iv[m0 * K_ + k];
        }
    }
    bf16x8 raw[K_];
    {
        const __bf16* xn = xb + ((size_t)(grp * 2) << 21);   // 4 MB slice
        #pragma unroll
        for (int k = 0; k < K_; ++k)
            raw[k] = *(const bf16x8*)(xn + (size_t)idxs[k] * FIN_ + kgrp * 8);
    }

    #pragma unroll
    for (int it = 0; it < ITERS_; ++it) {
        const bool hn = (it + 1) < ITERS_;

        // 1) next iteration's idx/iv loads (full iteration of latency budget)
        int   idxn[K_];
        float ivn[K_];
        if (hn) {
            const int mn = mb0 + ((it + 1) & 3) * 16 + col;
            #pragma unroll
            for (int k = 0; k < K_; ++k) {
                idxn[k] = il[mn * K_ + k];
                ivn[k]  = iv[mn * K_ + k];
            }
        }

        // 2) compute with gathers issued one iteration ago
        f32x4 acc0 = {0.f, 0.f, 0.f, 0.f};
        f32x4 acc1 = {0.f, 0.f, 0.f, 0.f};
        #pragma unroll
        for (int k = 0; k < K_; ++k) {
            const float ivk = ivs[k];
            bf16x8 a;
            #pragma unroll
            for (int j = 0; j < 8; ++j)
                a[j] = (__bf16)((float)raw[k][j] * ivk);
            const bf16x8 bf0 = *(const bf16x8*)(wlds + ((k * 2 + 0) * 64 + lane) * 8);
            const bf16x8 bf1 = *(const bf16x8*)(wlds + ((k * 2 + 1) * 64 + lane) * 8);
            acc0 = __builtin_amdgcn_mfma_f32_16x16x32_bf16(a, bf0, acc0, 0, 0, 0);
            acc1 = __builtin_amdgcn_mfma_f32_16x16x32_bf16(a, bf1, acc1, 0, 0, 0);
        }

        // 3) raw consumed — issue next iteration's gathers (crosses the
        //    phase boundary at it==3 -> slice n=grp*2+1)
        if (hn) {
            const __bf16* xn = xb + ((size_t)(grp * 2 + ((it + 1) >> 2)) << 21);
            #pragma unroll
            for (int k = 0; k < K_; ++k)
                raw[k] = *(const bf16x8*)(xn + (size_t)idxn[k] * FIN_ + kgrp * 8);
            #pragma unroll
            for (int k = 0; k < K_; ++k) { idxs[k] = idxn[k]; ivs[k] = ivn[k]; }
        }

        // 4) epilogue: D row = m offset (kgrp*4+r), D col = o.
        //    2 KB contiguous per iteration; nontemporal (write-once).
        const int n_cur = grp * 2 + (it >> 2);
        const int mb    = mb0 + (it & 3) * 16;
        #pragma unroll
        for (int r = 0; r < 4; ++r) {
            float* op = out + ((size_t)n_cur * M_ + (size_t)(mb + kgrp * 4 + r)) * FOUT_;
            __builtin_nontemporal_store(acc0[r] + b_lo, op + col);
            __builtin_nontemporal_store(acc1[r] + b_hi, op + 16 + col);
        }
    }
}

// ---------------------------------------------------------------------------
// Fallback if ws_size is too small for the bf16 staging.
// ---------------------------------------------------------------------------
__global__ __launch_bounds__(256, 4)
void gfc_fallback_kernel(const float* __restrict__ x,
                         const float* __restrict__ w,
                         const float* __restrict__ bias,
                         const int*   __restrict__ index_list,
                         const float* __restrict__ index_value,
                         float* __restrict__ out)
{
    const int lane  = threadIdx.x & 63;
    const int col   = lane & 15;
    const int kgrp  = lane >> 4;

    const int waves_per_block = blockDim.x >> 6;
    const int wave_id     = blockIdx.x * waves_per_block + (threadIdx.x >> 6);
    const int total_waves = gridDim.x * waves_per_block;

    bf16x8 bfrag[K_][2];
    #pragma unroll
    for (int k = 0; k < K_; ++k) {
        #pragma unroll
        for (int h = 0; h < 2; ++h) {
            const float* wp = w + (size_t)k * (FIN_ * FOUT_)
                                + (size_t)(kgrp * 8) * FOUT_ + h * 16 + col;
            bf16x8 b;
            #pragma unroll
            for (int j = 0; j < 8; ++j)
                b[j] = (__bf16)wp[j * FOUT_];
            bfrag[k][h] = b;
        }
    }
    const float b_lo = bias[col];
    const float b_hi = bias[16 + col];

    for (int m = wave_id; m < M_; m += total_waves) {
        f32x4 acc0 = {0.f, 0.f, 0.f, 0.f};
        f32x4 acc1 = {0.f, 0.f, 0.f, 0.f};

        #pragma unroll
        for (int k = 0; k < K_; ++k) {
            const int   m2  = index_list[m * K_ + k];
            const float ivk = index_value[m * K_ + k];
            const float* ap = x + ((size_t)col * M_ + (size_t)m2) * FIN_ + kgrp * 8;
            const float4 v0 = *(const float4*)(ap);
            const float4 v1 = *(const float4*)(ap + 4);
            const float av[8] = {v0.x, v0.y, v0.z, v0.w, v1.x, v1.y, v1.z, v1.w};
            bf16x8 a;
            #pragma unroll
            for (int j = 0; j < 8; ++j)
                a[j] = (__bf16)(av[j] * ivk);
            acc0 = __builtin_amdgcn_mfma_f32_16x16x32_bf16(a, bfrag[k][0], acc0, 0, 0, 0);
            acc1 = __builtin_amdgcn_mfma_f32_16x16x32_bf16(a, bfrag[k][1], acc1, 0, 0, 0);
        }

        #pragma unroll
        for (int r = 0; r < 4; ++r) {
            const int n = kgrp * 4 + r;
            const size_t base = ((size_t)n * M_ + (size_t)m) * FOUT_;
            out[base + col]      = acc0[r] + b_lo;
            out[base + 16 + col] = acc1[r] + b_hi;
        }
    }
}

extern "C" void kernel_launch(void* const* d_in, const int* in_sizes, int n_in,
                              void* d_out, int out_size, void* d_ws, size_t ws_size,
                              hipStream_t stream) {
    const float* x    = (const float*)d_in[0];  // (N, M, FIN) fp32
    const float* w    = (const float*)d_in[1];  // (K, FIN, FOUT) fp32
    const float* bias = (const float*)d_in[2];  // (FOUT,) fp32
    const int*   il   = (const int*)  d_in[3];  // (M*K,) int32
    const float* iv   = (const float*)d_in[4];  // (M, K) fp32
    float* out = (float*)d_out;                 // (N, M, FOUT) fp32

    const size_t ws_needed = (size_t)M_ * N_ * FIN_ * sizeof(__bf16);  // 64 MB
    if (ws_size >= ws_needed) {
        __bf16* xb = (__bf16*)d_ws;
        const int t_total = N_ * M_ * FIN_ / 8;   // 4,194,304 threads
        hipLaunchKernelGGL(convert_kernel, dim3(t_total / 256), dim3(256), 0, stream,
                           x, xb);
        hipLaunchKernelGGL(gfc_phase_kernel, dim3(BLOCKS_), dim3(THREADS_), 0, stream,
                           xb, w, bias, il, iv, out);
    } else {
        hipLaunchKernelGGL(gfc_fallback_kernel, dim3(2048), dim3(256), 0, stream,
                           x, w, bias, il, iv, out);
    }
}

// Round 5
// 315.858 us; speedup vs baseline: 1.8296x; 1.1620x over previous
//
#include <hip/hip_runtime.h>
#include <hip/hip_bf16.h>

// Problem constants: N=16, M=65536, FIN=32, FOUT=32, K=7
#define N_    16
#define M_    65536
#define FIN_  32
#define FOUT_ 32
#define K_    7

#define THREADS_   256
#define GBLOCKS_   1024               // blocks per gfc launch (~= tickets)
#define CHUNK_M_   512                // m per ticket (1 ticket ~ 1 block)
#define TICKETS_   (M_ / CHUNK_M_)    // 128 tickets per slice
#define ITERS_T_   8                  // 8 x 16 m per wave per ticket

typedef __bf16 bf16x8 __attribute__((ext_vector_type(8)));
typedef float  f32x4  __attribute__((ext_vector_type(4)));

// Ticket counters, one per (launch, slice): PADDED to 128 B each so the 8
// active counters live on 8 different home-L2 lines (round-3 lesson: all 16
// in one line serialized ~18k device-scope RMWs ~= the whole 229 us).
__device__ int g_tk[16 * 32];

// ---------------------------------------------------------------------------
// Pass 1: streaming fp32 -> bf16 convert, same (N,M,FIN) layout.
// Each n-slice xb[n] = 4 MB = one XCD L2. x loads nontemporal (dead after
// this); xb stores REGULAR (LLC-resident). Also re-zeroes ticket counters
// every replay (runs before both gfc launches on the same stream).
// ---------------------------------------------------------------------------
__global__ __launch_bounds__(256)
void convert_kernel(const float* __restrict__ x, __bf16* __restrict__ xb)
{
    if (blockIdx.x == 0 && threadIdx.x < 16) g_tk[threadIdx.x * 32] = 0;

    const size_t tid = (size_t)blockIdx.x * blockDim.x + threadIdx.x;
    const f32x4* src = (const f32x4*)x + tid * 2;
    const f32x4 v0 = __builtin_nontemporal_load(src);
    const f32x4 v1 = __builtin_nontemporal_load(src + 1);
    bf16x8 b;
    #pragma unroll
    for (int j = 0; j < 4; ++j) b[j] = (__bf16)v0[j];
    #pragma unroll
    for (int j = 0; j < 4; ++j) b[4 + j] = (__bf16)v1[j];
    *(bf16x8*)(xb + tid * 8) = b;
}

// ---------------------------------------------------------------------------
// Pass 2 (x2 launches): XCC-exact L2-resident gathers, low-overhead tickets.
//   - Slice by REAL XCD id (R3-proven: FETCH hits the 62 MB floor).
//   - Launch L: XCD c sweeps all m for n = L*8+c. Kernel boundary = hard
//     phase separation (R4 lesson: structural phasing drifts -> L2 thrash).
//   - 1 ticket = 512 m ~ 1 block; ~2 RMW + 7 mostly-read probes per block
//     on padded lines (R3 lesson: atomic serialization, not memory, was
//     the cost). Monotone counters let probes use plain loads safely.
//   - Work-stealing sweep guarantees coverage whatever the dispatch balance.
//   - Flat 8-iter software pipeline per ticket (R0-proven depth).
// ---------------------------------------------------------------------------
__global__ __launch_bounds__(256, 4)
void gfc_tk_kernel(const __bf16* __restrict__ xb,
                   const float* __restrict__ w,
                   const float* __restrict__ bias,
                   const int*   __restrict__ il,
                   const float* __restrict__ iv,
                   float* __restrict__ out,
                   const int launch)
{
    __shared__ __bf16 wlds[K_ * 2 * 64 * 8];   // [k][h][lane][8] = 14 KB
    __shared__ int t_sh;

    const int lane = threadIdx.x & 63;
    const int col  = lane & 15;   // A-row (m offset in group of 16) / C-col (o)
    const int kgrp = lane >> 4;   // 8-wide f-chunk
    const int wv   = threadIdx.x >> 6;

    // Stage B fragments once per block: frag[k][h][lane][j] = w[k][kg*8+j][h*16+c]
    for (int t = threadIdx.x; t < K_ * 2 * 64; t += THREADS_) {
        const int l  = t & 63;
        const int h  = (t >> 6) & 1;
        const int k  = t >> 7;
        const int c  = l & 15;
        const int kg = l >> 4;
        const float* wp = w + (size_t)k * (FIN_ * FOUT_)
                            + (size_t)(kg * 8) * FOUT_ + h * 16 + c;
        bf16x8 b;
        #pragma unroll
        for (int j = 0; j < 8; ++j) b[j] = (__bf16)wp[j * FOUT_];
        *(bf16x8*)(wlds + (size_t)t * 8) = b;
    }
    __syncthreads();

    const float b_lo = bias[col];
    const float b_hi = bias[16 + col];

    unsigned xcc_raw;
    asm volatile("s_getreg_b32 %0, hwreg(HW_REG_XCC_ID, 0, 32)" : "=s"(xcc_raw));
    const int xcc = (int)(xcc_raw & 7u);

    for (int s = 0; s < 8; ++s) {
        const int q = (xcc + s) & 7;               // own slice first, then steal
        const int n = launch * 8 + q;
        const __bf16* xn = xb + ((size_t)n << 21); // 4 MB slice
        int* tq = &g_tk[(launch * 8 + q) * 32];

        for (;;) {
            __syncthreads();                       // protect t_sh reuse
            if (threadIdx.x == 0) {
                // Counters only grow; a (possibly stale) plain load can only
                // under-read -> skipping the RMW when it reads >= TICKETS_ is
                // safe and turns most drain probes into read-only traffic.
                const int est = *(volatile int*)tq;
                t_sh = (est >= TICKETS_) ? TICKETS_ : atomicAdd(tq, 1);
            }
            __syncthreads();
            const int t = t_sh;
            if (t >= TICKETS_) break;

            const int m_base = t * CHUNK_M_ + wv * (CHUNK_M_ / 4);  // wave's 128 m

            // ---- flat 8-iteration pipeline over this ticket ----
            float ivs[K_];
            bf16x8 raw[K_];
            {
                const int m0 = m_base + col;
                int idx0[K_];
                #pragma unroll
                for (int k = 0; k < K_; ++k) {
                    idx0[k] = il[m0 * K_ + k];
                    ivs[k]  = iv[m0 * K_ + k];
                }
                #pragma unroll
                for (int k = 0; k < K_; ++k)
                    raw[k] = *(const bf16x8*)(xn + (size_t)idx0[k] * FIN_ + kgrp * 8);
            }

            #pragma unroll
            for (int it = 0; it < ITERS_T_; ++it) {
                const bool hn = (it + 1) < ITERS_T_;

                // 1) next iteration's idx/iv
                int   idxn[K_];
                float ivn[K_];
                if (hn) {
                    const int mn = m_base + (it + 1) * 16 + col;
                    #pragma unroll
                    for (int k = 0; k < K_; ++k) {
                        idxn[k] = il[mn * K_ + k];
                        ivn[k]  = iv[mn * K_ + k];
                    }
                }

                // 2) compute with gathers issued one iteration ago
                f32x4 acc0 = {0.f, 0.f, 0.f, 0.f};
                f32x4 acc1 = {0.f, 0.f, 0.f, 0.f};
                #pragma unroll
                for (int k = 0; k < K_; ++k) {
                    const float ivk = ivs[k];
                    bf16x8 a;
                    #pragma unroll
                    for (int j = 0; j < 8; ++j)
                        a[j] = (__bf16)((float)raw[k][j] * ivk);
                    const bf16x8 bf0 = *(const bf16x8*)(wlds + ((k * 2 + 0) * 64 + lane) * 8);
                    const bf16x8 bf1 = *(const bf16x8*)(wlds + ((k * 2 + 1) * 64 + lane) * 8);
                    acc0 = __builtin_amdgcn_mfma_f32_16x16x32_bf16(a, bf0, acc0, 0, 0, 0);
                    acc1 = __builtin_amdgcn_mfma_f32_16x16x32_bf16(a, bf1, acc1, 0, 0, 0);
                }

                // 3) issue next iteration's gathers
                if (hn) {
                    #pragma unroll
                    for (int k = 0; k < K_; ++k)
                        raw[k] = *(const bf16x8*)(xn + (size_t)idxn[k] * FIN_ + kgrp * 8);
                    #pragma unroll
                    for (int k = 0; k < K_; ++k) ivs[k] = ivn[k];
                }

                // 4) epilogue: D row = m offset (kgrp*4+r), D col = o.
                //    2 KB contiguous per iteration; nontemporal (write-once).
                const int mb = m_base + it * 16;
                #pragma unroll
                for (int r = 0; r < 4; ++r) {
                    float* op = out + ((size_t)n * M_ + (size_t)(mb + kgrp * 4 + r)) * FOUT_;
                    __builtin_nontemporal_store(acc0[r] + b_lo, op + col);
                    __builtin_nontemporal_store(acc1[r] + b_hi, op + 16 + col);
                }
            }
        }
    }
}

// ---------------------------------------------------------------------------
// Fallback if ws_size is too small for the bf16 staging.
// ---------------------------------------------------------------------------
__global__ __launch_bounds__(256, 4)
void gfc_fallback_kernel(const float* __restrict__ x,
                         const float* __restrict__ w,
                         const float* __restrict__ bias,
                         const int*   __restrict__ index_list,
                         const float* __restrict__ index_value,
                         float* __restrict__ out)
{
    const int lane  = threadIdx.x & 63;
    const int col   = lane & 15;
    const int kgrp  = lane >> 4;

    const int waves_per_block = blockDim.x >> 6;
    const int wave_id     = blockIdx.x * waves_per_block + (threadIdx.x >> 6);
    const int total_waves = gridDim.x * waves_per_block;

    bf16x8 bfrag[K_][2];
    #pragma unroll
    for (int k = 0; k < K_; ++k) {
        #pragma unroll
        for (int h = 0; h < 2; ++h) {
            const float* wp = w + (size_t)k * (FIN_ * FOUT_)
                                + (size_t)(kgrp * 8) * FOUT_ + h * 16 + col;
            bf16x8 b;
            #pragma unroll
            for (int j = 0; j < 8; ++j)
                b[j] = (__bf16)wp[j * FOUT_];
            bfrag[k][h] = b;
        }
    }
    const float b_lo = bias[col];
    const float b_hi = bias[16 + col];

    for (int m = wave_id; m < M_; m += total_waves) {
        f32x4 acc0 = {0.f, 0.f, 0.f, 0.f};
        f32x4 acc1 = {0.f, 0.f, 0.f, 0.f};

        #pragma unroll
        for (int k = 0; k < K_; ++k) {
            const int   m2  = index_list[m * K_ + k];
            const float ivk = index_value[m * K_ + k];
            const float* ap = x + ((size_t)col * M_ + (size_t)m2) * FIN_ + kgrp * 8;
            const float4 v0 = *(const float4*)(ap);
            const float4 v1 = *(const float4*)(ap + 4);
            const float av[8] = {v0.x, v0.y, v0.z, v0.w, v1.x, v1.y, v1.z, v1.w};
            bf16x8 a;
            #pragma unroll
            for (int j = 0; j < 8; ++j)
                a[j] = (__bf16)(av[j] * ivk);
            acc0 = __builtin_amdgcn_mfma_f32_16x16x32_bf16(a, bfrag[k][0], acc0, 0, 0, 0);
            acc1 = __builtin_amdgcn_mfma_f32_16x16x32_bf16(a, bfrag[k][1], acc1, 0, 0, 0);
        }

        #pragma unroll
        for (int r = 0; r < 4; ++r) {
            const int n = kgrp * 4 + r;
            const size_t base = ((size_t)n * M_ + (size_t)m) * FOUT_;
            out[base + col]      = acc0[r] + b_lo;
            out[base + 16 + col] = acc1[r] + b_hi;
        }
    }
}

extern "C" void kernel_launch(void* const* d_in, const int* in_sizes, int n_in,
                              void* d_out, int out_size, void* d_ws, size_t ws_size,
                              hipStream_t stream) {
    const float* x    = (const float*)d_in[0];  // (N, M, FIN) fp32
    const float* w    = (const float*)d_in[1];  // (K, FIN, FOUT) fp32
    const float* bias = (const float*)d_in[2];  // (FOUT,) fp32
    const int*   il   = (const int*)  d_in[3];  // (M*K,) int32
    const float* iv   = (const float*)d_in[4];  // (M, K) fp32
    float* out = (float*)d_out;                 // (N, M, FOUT) fp32

    const size_t ws_needed = (size_t)M_ * N_ * FIN_ * sizeof(__bf16);  // 64 MB
    if (ws_size >= ws_needed) {
        __bf16* xb = (__bf16*)d_ws;
        const int t_total = N_ * M_ * FIN_ / 8;   // 4,194,304 threads
        hipLaunchKernelGGL(convert_kernel, dim3(t_total / 256), dim3(256), 0, stream,
                           x, xb);
        hipLaunchKernelGGL(gfc_tk_kernel, dim3(GBLOCKS_), dim3(THREADS_), 0, stream,
                           xb, w, bias, il, iv, out, 0);
        hipLaunchKernelGGL(gfc_tk_kernel, dim3(GBLOCKS_), dim3(THREADS_), 0, stream,
                           xb, w, bias, il, iv, out, 1);
    } else {
        hipLaunchKernelGGL(gfc_fallback_kernel, dim3(2048), dim3(256), 0, stream,
                           x, w, bias, il, iv, out);
    }
}